// Round 21
// baseline (237.179 us; speedup 1.0000x reference)
//
#include <hip/hip_runtime.h>
#include <hip/hip_bf16.h>

// Problem constants (B=2, S=2048, D=512, H=8, hd=64)
constexpr int Bc = 2, Sc = 2048, Dc = 512, Hc = 8, HDc = 64;
constexpr int Mtot = Bc * Sc;    // 4096
constexpr size_t HEADMAT = (size_t)Bc * Hc * Sc * HDc;  // 2M elems
// softmax in log2 domain
constexpr float SC2  = 0.18033688011112042f;   // 0.125 * log2(e)
constexpr float NEG2 = 14426.950408889634f;    // 10000 * log2(e)

typedef __attribute__((ext_vector_type(8)))  short          short8;
typedef __attribute__((ext_vector_type(8)))  unsigned short ushort8;
typedef __attribute__((ext_vector_type(4)))  float          f32x4;
typedef __attribute__((ext_vector_type(16))) float          f32x16;

#define MFMA16 __builtin_amdgcn_mfma_f32_16x16x32_bf16
#define MFMA32 __builtin_amdgcn_mfma_f32_32x32x16_bf16

static __device__ __forceinline__ unsigned short f32_to_bf16_bits(float f) {
    unsigned int u = __builtin_bit_cast(unsigned int, f);
    unsigned int r = u + 0x7FFFu + ((u >> 16) & 1u);   // RNE
    return (unsigned short)(r >> 16);
}
static __device__ __forceinline__ unsigned int pk2bf(float a, float b) {
    union { __hip_bfloat162 h2; unsigned int u; } cv;
    cv.h2 = __float22bfloat162_rn(make_float2(a, b));   // HW v_cvt_pk path
    return cv.u;
}

// ---------------------------------------------------------------------------
// W -> W^T bf16
// ---------------------------------------------------------------------------
__global__ __launch_bounds__(256)
void transpose_w(const float* __restrict__ W0, const float* __restrict__ W1,
                 const float* __restrict__ W2, const float* __restrict__ W3,
                 unsigned short* __restrict__ Wt)
{
    __shared__ float T[64][65];
    const int z = blockIdx.z;
    const float* Wp = (z == 0) ? W0 : (z == 1) ? W1 : (z == 2) ? W2 : W3;
    unsigned short* Op = Wt + (size_t)z * 512 * 512;

    const int kt = blockIdx.y * 64, nt = blockIdx.x * 64;
    const int t = threadIdx.x;
    const int r  = t >> 2, c4 = (t & 3) * 16;

    #pragma unroll
    for (int i = 0; i < 4; ++i) {
        const float4 v = *(const float4*)(Wp + (size_t)(kt + r) * 512 + nt + c4 + 4 * i);
        T[r][c4 + 4*i + 0] = v.x;
        T[r][c4 + 4*i + 1] = v.y;
        T[r][c4 + 4*i + 2] = v.z;
        T[r][c4 + 4*i + 3] = v.w;
    }
    __syncthreads();

    const int n = t >> 2, k4 = (t & 3) * 16;
    #pragma unroll
    for (int i = 0; i < 4; ++i) {
        ushort4 o;
        o.x = f32_to_bf16_bits(T[k4 + 4*i + 0][n]);
        o.y = f32_to_bf16_bits(T[k4 + 4*i + 1][n]);
        o.z = f32_to_bf16_bits(T[k4 + 4*i + 2][n]);
        o.w = f32_to_bf16_bits(T[k4 + 4*i + 3][n]);
        *(ushort4*)(Op + (size_t)(nt + n) * 512 + kt + k4 + 4 * i) = o;
    }
}

// ---------------------------------------------------------------------------
// Tiled bf16 MFMA GEMM (verified; R20 version with fused x conversion).
// ---------------------------------------------------------------------------
template<bool HEADOUT>
__global__ __launch_bounds__(256)
void gemm_tile(const void* __restrict__ Asrc,
               const unsigned short* __restrict__ Wt,
               const float* __restrict__ b0, const float* __restrict__ b1,
               const float* __restrict__ b2,
               unsigned short* __restrict__ Hout,
               float* __restrict__ Yf)
{
    __shared__ short As[128 * 32];
    __shared__ short Bs[64 * 32];

    const int lane = threadIdx.x & 63, wave = threadIdx.x >> 6;
    const int c = lane & 15, g = lane >> 4;
    const int wr = wave >> 1, wc = wave & 1;
    const int z = blockIdx.z;
    const unsigned short* Wp = Wt + (size_t)z * 512 * 512;
    const float* bp = (z == 0) ? b0 : (z == 1) ? b1 : b2;
    const int bm = blockIdx.y * 128;
    const int bn = blockIdx.x * 64;

    const int srow = lane >> 2;
    const int scol = (lane & 3) * 8;

    f32x4 acc[4][2] = {};

    for (int k0 = 0; k0 < 512; k0 += 32) {
        __syncthreads();
        #pragma unroll
        for (int i = 0; i < 2; ++i) {
            const int row = (wave * 2 + i) * 16 + srow;
            if constexpr (HEADOUT) {
                const float* xp = (const float*)Asrc +
                                  (size_t)(bm + row) * 512 + k0 + scol;
                const float4 v0 = *(const float4*)(xp);
                const float4 v1 = *(const float4*)(xp + 4);
                union { unsigned int u[4]; short8 s; } pk;
                pk.u[0] = pk2bf(v0.x, v0.y);
                pk.u[1] = pk2bf(v0.z, v0.w);
                pk.u[2] = pk2bf(v1.x, v1.y);
                pk.u[3] = pk2bf(v1.z, v1.w);
                *(short8*)(&As[row * 32 + scol]) = pk.s;
            } else {
                const short8 v = *(const short8*)((const unsigned short*)Asrc +
                                  (size_t)(bm + row) * 512 + k0 + scol);
                *(short8*)(&As[row * 32 + scol]) = v;
            }
        }
        {
            const int row = wave * 16 + srow;
            const short8 v = *(const short8*)(Wp + (size_t)(bn + row) * 512 + k0 + scol);
            *(short8*)(&Bs[row * 32 + scol]) = v;
        }
        __syncthreads();

        short8 a[4], bfr[2];
        #pragma unroll
        for (int mi = 0; mi < 4; ++mi)
            a[mi] = *(const short8*)(&As[(wr * 64 + mi * 16 + c) * 32 + g * 8]);
        #pragma unroll
        for (int ni = 0; ni < 2; ++ni)
            bfr[ni] = *(const short8*)(&Bs[(wc * 32 + ni * 16 + c) * 32 + g * 8]);
        #pragma unroll
        for (int mi = 0; mi < 4; ++mi)
            #pragma unroll
            for (int ni = 0; ni < 2; ++ni)
                acc[mi][ni] = MFMA16(a[mi], bfr[ni], acc[mi][ni], 0, 0, 0);
    }

    #pragma unroll
    for (int mi = 0; mi < 4; ++mi) {
        #pragma unroll
        for (int ni = 0; ni < 2; ++ni) {
            const int n = bn + wc * 32 + ni * 16 + c;
            const float bias = bp[n];
            float v[4];
            #pragma unroll
            for (int r = 0; r < 4; ++r) {
                v[r] = fmaxf(acc[mi][ni][r] + bias, 0.0f);
                if (HEADOUT && z == 0) v[r] *= SC2;   // pre-scale Q
            }
            const int mbase = bm + wr * 64 + mi * 16 + 4 * g;
            if constexpr (HEADOUT) {
                const int bb = mbase >> 11, ss = mbase & 2047;
                const int hh = n >> 6, hd = n & 63;
                if (z == 2) {
                    union { ushort4 u; unsigned short s[4]; } pk;
                    #pragma unroll
                    for (int r = 0; r < 4; ++r) pk.s[r] = f32_to_bf16_bits(v[r]);
                    *reinterpret_cast<ushort4*>(
                        Hout + (size_t)2 * HEADMAT +
                        (size_t)(bb * Hc + hh) * Sc * HDc +
                        (size_t)(ss >> 5) * (HDc * 32) + hd * 32 + (ss & 31)) = pk.u;
                } else {
                    #pragma unroll
                    for (int r = 0; r < 4; ++r)
                        Hout[(size_t)z * HEADMAT +
                             (((size_t)(bb * Hc + hh) * Sc + ss + r) * HDc + hd)] =
                            f32_to_bf16_bits(v[r]);
                }
            } else {
                #pragma unroll
                for (int r = 0; r < 4; ++r)
                    Yf[(size_t)(mbase + r) * 512 + n] = v[r];
            }
        }
    }
}

// ---------------------------------------------------------------------------
// Split-K flash attention, ABLATION build (template<VAR>):
//  VAR 0: full (R18/R20-verified path, real output)
//  VAR 1: QK skeleton only (K loads + 4 MFMA + acc keep-alive)
//  VAR 2: + mask + softmax (ballot, e/tmax, shfl, rescale, exp2, l)
//  VAR 3: + P pack & cross-half exchange (asm keep-alive; no V/PV)
//  VAR 4: full minus softmax (s packed directly; V loads + PV)
// All variants: identical grid/launch/epilogue (tail effects included).
// ---------------------------------------------------------------------------
template<int VAR>
__global__ __launch_bounds__(256)
void attn_mfma(const short* __restrict__ Qh, const short* __restrict__ Kh,
               const short* __restrict__ Vb, const int* __restrict__ mask,
               unsigned short* __restrict__ Ob)
{
    __shared__ __align__(16) char smem[4 * 8448 + 4 * 256];

    const int lane = threadIdx.x & 63;
    const int wave = threadIdx.x >> 6;
    const int bid  = blockIdx.x;                    // 1024 blocks
    const int swz  = (bid & 7) * 128 + (bid >> 3);  // XCD-chunked, bijective
    const int t    = 63 - (swz & 63);               // LPT: big tiles first
    const int h    = (swz >> 6) & 7;
    const int b    = swz >> 9;
    const int q0   = t * 32;
    const int r32  = lane & 31;
    const int hi   = lane >> 5;

    char*  wreg = smem + wave * 8448;
    float* Lml  = (float*)(smem + 4 * 8448 + wave * 256);

    const size_t headoff = (size_t)(b * Hc + h) * Sc * HDc;
    const short* Qp = Qh + headoff;
    const short* Kp = Kh + headoff;
    const short* Vp = Vb + headoff;                 // blocked [S/32][64][32]
    const int* mb = mask + b * Sc;

    int fb = Sc;
    for (int base = 0; base < Sc; base += 64) {
        unsigned long long bal = __ballot(mb[base + lane] != 0);
        if (bal) { fb = base + (__ffsll(bal) - 1); break; }
    }
    const int kmax = (fb <= q0) ? (q0 + 32) : Sc;
    const int kend = (kmax + 31) & ~31;
    const int nT   = kend >> 5;
    const int tpw  = (nT + 3) >> 2;
    const int kbeg = wave * tpw * 32;
    const int kfin = min(kend, kbeg + tpw * 32);

    short8 qf[4];
    #pragma unroll
    for (int j = 0; j < 4; ++j)
        qf[j] = *(const short8*)(Qp + (size_t)(q0 + r32) * HDc + j * 16 + hi * 8);

    f32x16 acc0 = {0,0,0,0,0,0,0,0,0,0,0,0,0,0,0,0};
    f32x16 acc1 = {0,0,0,0,0,0,0,0,0,0,0,0,0,0,0,0};
    float m = -1e30f, l = 0.0f;

    const int vo0 = r32 * 32 + 8 * hi;
    const int vo1 = (32 + r32) * 32 + 8 * hi;

    for (int k0 = kbeg; k0 < kfin; k0 += 32) {
        // --- V fragments (only variants that run PV)
        short8 va0, va1, vb0, vb1;
        if constexpr (VAR == 0 || VAR == 4) {
            const short* vpan = Vp + (size_t)k0 * 64;
            va0 = *(const short8*)(vpan + vo0);
            va1 = *(const short8*)(vpan + vo0 + 16);
            vb0 = *(const short8*)(vpan + vo1);
            vb1 = *(const short8*)(vpan + vo1 + 16);
        }

        // --- K fragments + QK^T (all variants)
        f32x16 s = {0,0,0,0,0,0,0,0,0,0,0,0,0,0,0,0};
        #pragma unroll
        for (int j = 0; j < 4; ++j) {
            const short8 kf =
                *(const short8*)(Kp + (size_t)(k0 + r32) * HDc + j * 16 + hi * 8);
            s = MFMA32(kf, qf[j], s, 0, 0, 0);
        }

        if constexpr (VAR == 1) {
            acc0 += s;     // keep-alive: prevents DCE of QK (rule #17)
        } else {
            float e[16];
            if constexpr (VAR == 0 || VAR == 2 || VAR == 3) {
                // --- mask + causal + online softmax
                const unsigned long long bal = __ballot(mb[k0 + r32] != 0);
                const unsigned int mloc = ((unsigned int)bal) >> (4 * hi);
                float tmax = -1e30f;
                if (k0 + 31 > q0) {
                    #pragma unroll
                    for (int r = 0; r < 16; ++r) {
                        const int cr0 = (r & 3) + 8 * (r >> 2);
                        float ev = s[r];
                        if (!((mloc >> cr0) & 1))            ev -= NEG2;
                        if (k0 + cr0 + 4 * hi > q0 + r32)    ev -= NEG2;
                        e[r] = ev;
                        tmax = fmaxf(tmax, ev);
                    }
                } else {
                    #pragma unroll
                    for (int r = 0; r < 16; ++r) {
                        const int cr0 = (r & 3) + 8 * (r >> 2);
                        float ev = s[r];
                        if (!((mloc >> cr0) & 1))            ev -= NEG2;
                        e[r] = ev;
                        tmax = fmaxf(tmax, ev);
                    }
                }
                tmax = fmaxf(tmax, __shfl_xor(tmax, 32));
                if (__any(tmax > m)) {
                    const float mn   = fmaxf(m, tmax);
                    const float corr = __builtin_exp2f(m - mn);
                    m = mn; l *= corr;
                    acc0 *= corr;
                    acc1 *= corr;
                }
                float ps = 0.f;
                #pragma unroll
                for (int r = 0; r < 16; ++r) {
                    e[r] = __builtin_exp2f(e[r] - m);
                    ps += e[r];
                }
                l += ps;
            } else {   // VAR == 4: no softmax, pack raw scores
                #pragma unroll
                for (int r = 0; r < 16; ++r) e[r] = s[r];
            }

            if constexpr (VAR != 2) {
                // --- pack P pairs + cross-half exchange
                const unsigned int A0 = pk2bf(e[0],  e[1]),  B0 = pk2bf(e[2],  e[3]);
                const unsigned int C0 = pk2bf(e[4],  e[5]),  D0 = pk2bf(e[6],  e[7]);
                const unsigned int A1 = pk2bf(e[8],  e[9]),  B1 = pk2bf(e[10], e[11]);
                const unsigned int C1 = pk2bf(e[12], e[13]), D1 = pk2bf(e[14], e[15]);
                const unsigned int A0s = (unsigned int)__shfl_xor((int)A0, 32);
                const unsigned int B0s = (unsigned int)__shfl_xor((int)B0, 32);
                const unsigned int C0s = (unsigned int)__shfl_xor((int)C0, 32);
                const unsigned int D0s = (unsigned int)__shfl_xor((int)D0, 32);
                const unsigned int A1s = (unsigned int)__shfl_xor((int)A1, 32);
                const unsigned int B1s = (unsigned int)__shfl_xor((int)B1, 32);
                const unsigned int C1s = (unsigned int)__shfl_xor((int)C1, 32);
                const unsigned int D1s = (unsigned int)__shfl_xor((int)D1, 32);

                union { unsigned int u[4]; short8 s8; } P0, P1;
                P0.u[0] = hi ? C0s : A0;  P0.u[1] = hi ? D0s : B0;
                P0.u[2] = hi ? C0  : A0s; P0.u[3] = hi ? D0  : B0s;
                P1.u[0] = hi ? C1s : A1;  P1.u[1] = hi ? D1s : B1;
                P1.u[2] = hi ? C1  : A1s; P1.u[3] = hi ? D1  : B1s;

                if constexpr (VAR == 3) {
                    // keep-alive only (no V/PV)
                    asm volatile("" :: "v"(P0.u[0]), "v"(P0.u[1]),
                                       "v"(P0.u[2]), "v"(P0.u[3]));
                    asm volatile("" :: "v"(P1.u[0]), "v"(P1.u[1]),
                                       "v"(P1.u[2]), "v"(P1.u[3]));
                } else {
                    acc0 = MFMA32(va0, P0.s8, acc0, 0, 0, 0);
                    acc0 = MFMA32(va1, P1.s8, acc0, 0, 0, 0);
                    acc1 = MFMA32(vb0, P0.s8, acc1, 0, 0, 0);
                    acc1 = MFMA32(vb1, P1.s8, acc1, 0, 0, 0);
                }
            }
        }
    }

    l += __shfl_xor(l, 32);

    {
        float* Lacc = (float*)wreg;   // [64][33]
        #pragma unroll
        for (int r = 0; r < 16; ++r) {
            Lacc[lane * 33 + r]      = acc0[r];
            Lacc[lane * 33 + 16 + r] = acc1[r];
        }
        if (lane < 32) { Lml[lane] = m; Lml[32 + lane] = l; }
    }
    __syncthreads();

    float mu[4], lu[4], M = -1e30f;
    #pragma unroll
    for (int u = 0; u < 4; ++u) {
        const float* LmlU = (const float*)(smem + 4 * 8448 + u * 256);
        mu[u] = LmlU[r32];
        lu[u] = LmlU[32 + r32];
        M = fmaxf(M, mu[u]);
    }
    float wgt[4], L = 0.f;
    #pragma unroll
    for (int u = 0; u < 4; ++u) {
        wgt[u] = __builtin_exp2f(mu[u] - M);
        L += wgt[u] * lu[u];
    }
    const float invL = 1.0f / L;

    #pragma unroll
    for (int jj = 0; jj < 8; ++jj) {
        const int j = wave * 8 + jj;
        float o = 0.f;
        #pragma unroll
        for (int u = 0; u < 4; ++u)
            o += wgt[u] * ((const float*)(smem + u * 8448))[lane * 33 + j];
        const int j16 = j & 15;
        const int d = (j16 & 3) + 8 * (j16 >> 2) + 4 * hi + 32 * (j >> 4);
        Ob[(size_t)(b * Sc + q0 + r32) * Dc + h * HDc + d] =
            f32_to_bf16_bits(o * invL);
    }
}

// ---------------------------------------------------------------------------
extern "C" void kernel_launch(void* const* d_in, const int* in_sizes, int n_in,
                              void* d_out, int out_size, void* d_ws, size_t ws_size,
                              hipStream_t stream) {
    const float* x  = (const float*)d_in[0];
    const int* mask = (const int*)d_in[1];
    const float* Wq = (const float*)d_in[2];
    const float* bq = (const float*)d_in[3];
    const float* Wk = (const float*)d_in[4];
    const float* bk = (const float*)d_in[5];
    const float* Wv = (const float*)d_in[6];
    const float* bv = (const float*)d_in[7];
    const float* Wo = (const float*)d_in[8];
    const float* bo = (const float*)d_in[9];
    float* out = (float*)d_out;   // reference output dtype is float32

    unsigned short* Wt   = (unsigned short*)d_ws;        // 2 MB
    unsigned short* Qh   = Wt + (size_t)4 * 512 * 512;   // head-major (xSC2)
    unsigned short* Kh   = Qh + HEADMAT;                 // head-major
    unsigned short* Vb   = Kh + HEADMAT;                 // BLOCKED panels
    unsigned short* Ob   = Vb + HEADMAT;                 // attention out
    unsigned short* Oscr = Ob + HEADMAT;                 // ablation scratch

    transpose_w<<<dim3(8, 8, 4), dim3(256), 0, stream>>>(Wq, Wk, Wv, Wo, Wt);
    gemm_tile<true><<<dim3(8, Mtot / 128, 3), dim3(256), 0, stream>>>(
        x, Wt, bq, bk, bv, Qh, nullptr);

    // ---- ablation dispatches (scratch output), then the real one ----
    attn_mfma<1><<<dim3(1024), dim3(256), 0, stream>>>(
        (const short*)Qh, (const short*)Kh, (const short*)Vb, mask, Oscr);
    attn_mfma<2><<<dim3(1024), dim3(256), 0, stream>>>(
        (const short*)Qh, (const short*)Kh, (const short*)Vb, mask, Oscr);
    attn_mfma<3><<<dim3(1024), dim3(256), 0, stream>>>(
        (const short*)Qh, (const short*)Kh, (const short*)Vb, mask, Oscr);
    attn_mfma<4><<<dim3(1024), dim3(256), 0, stream>>>(
        (const short*)Qh, (const short*)Kh, (const short*)Vb, mask, Oscr);
    attn_mfma<0><<<dim3(1024), dim3(256), 0, stream>>>(
        (const short*)Qh, (const short*)Kh, (const short*)Vb, mask, Ob);

    gemm_tile<false><<<dim3(8, Mtot / 128, 1), dim3(256), 0, stream>>>(
        Ob, Wt + (size_t)3 * 512 * 512, bo, bo, bo, nullptr, out);
}

// Round 22
// 87.962 us; speedup vs baseline: 2.6964x; 2.6964x over previous
//
#include <hip/hip_runtime.h>
#include <hip/hip_bf16.h>

// Problem constants (B=2, S=2048, D=512, H=8, hd=64)
constexpr int Bc = 2, Sc = 2048, Dc = 512, Hc = 8, HDc = 64;
constexpr int Mtot = Bc * Sc;    // 4096
constexpr size_t HEADMAT = (size_t)Bc * Hc * Sc * HDc;  // 2M elems
// softmax in log2 domain
constexpr float SC2  = 0.18033688011112042f;   // 0.125 * log2(e)
constexpr float NEG2 = 14426.950408889634f;    // 10000 * log2(e)

typedef __attribute__((ext_vector_type(8)))  short          short8;
typedef __attribute__((ext_vector_type(8)))  unsigned short ushort8;
typedef __attribute__((ext_vector_type(4)))  float          f32x4;
typedef __attribute__((ext_vector_type(16))) float          f32x16;

#define MFMA16 __builtin_amdgcn_mfma_f32_16x16x32_bf16
#define MFMA32 __builtin_amdgcn_mfma_f32_32x32x16_bf16

static __device__ __forceinline__ unsigned short f32_to_bf16_bits(float f) {
    unsigned int u = __builtin_bit_cast(unsigned int, f);
    unsigned int r = u + 0x7FFFu + ((u >> 16) & 1u);   // RNE
    return (unsigned short)(r >> 16);
}
static __device__ __forceinline__ unsigned int pk2bf(float a, float b) {
    union { __hip_bfloat162 h2; unsigned int u; } cv;
    cv.h2 = __float22bfloat162_rn(make_float2(a, b));   // HW v_cvt_pk path
    return cv.u;
}

// ---------------------------------------------------------------------------
// W -> W^T bf16
// ---------------------------------------------------------------------------
__global__ __launch_bounds__(256)
void transpose_w(const float* __restrict__ W0, const float* __restrict__ W1,
                 const float* __restrict__ W2, const float* __restrict__ W3,
                 unsigned short* __restrict__ Wt)
{
    __shared__ float T[64][65];
    const int z = blockIdx.z;
    const float* Wp = (z == 0) ? W0 : (z == 1) ? W1 : (z == 2) ? W2 : W3;
    unsigned short* Op = Wt + (size_t)z * 512 * 512;

    const int kt = blockIdx.y * 64, nt = blockIdx.x * 64;
    const int t = threadIdx.x;
    const int r  = t >> 2, c4 = (t & 3) * 16;

    #pragma unroll
    for (int i = 0; i < 4; ++i) {
        const float4 v = *(const float4*)(Wp + (size_t)(kt + r) * 512 + nt + c4 + 4 * i);
        T[r][c4 + 4*i + 0] = v.x;
        T[r][c4 + 4*i + 1] = v.y;
        T[r][c4 + 4*i + 2] = v.z;
        T[r][c4 + 4*i + 3] = v.w;
    }
    __syncthreads();

    const int n = t >> 2, k4 = (t & 3) * 16;
    #pragma unroll
    for (int i = 0; i < 4; ++i) {
        ushort4 o;
        o.x = f32_to_bf16_bits(T[k4 + 4*i + 0][n]);
        o.y = f32_to_bf16_bits(T[k4 + 4*i + 1][n]);
        o.z = f32_to_bf16_bits(T[k4 + 4*i + 2][n]);
        o.w = f32_to_bf16_bits(T[k4 + 4*i + 3][n]);
        *(ushort4*)(Op + (size_t)(nt + n) * 512 + kt + k4 + 4 * i) = o;
    }
}

// ---------------------------------------------------------------------------
// Tiled bf16 MFMA GEMM (verified; R20 version with fused x conversion).
// ---------------------------------------------------------------------------
template<bool HEADOUT>
__global__ __launch_bounds__(256)
void gemm_tile(const void* __restrict__ Asrc,
               const unsigned short* __restrict__ Wt,
               const float* __restrict__ b0, const float* __restrict__ b1,
               const float* __restrict__ b2,
               unsigned short* __restrict__ Hout,
               float* __restrict__ Yf)
{
    __shared__ short As[128 * 32];
    __shared__ short Bs[64 * 32];

    const int lane = threadIdx.x & 63, wave = threadIdx.x >> 6;
    const int c = lane & 15, g = lane >> 4;
    const int wr = wave >> 1, wc = wave & 1;
    const int z = blockIdx.z;
    const unsigned short* Wp = Wt + (size_t)z * 512 * 512;
    const float* bp = (z == 0) ? b0 : (z == 1) ? b1 : b2;
    const int bm = blockIdx.y * 128;
    const int bn = blockIdx.x * 64;

    const int srow = lane >> 2;
    const int scol = (lane & 3) * 8;

    f32x4 acc[4][2] = {};

    for (int k0 = 0; k0 < 512; k0 += 32) {
        __syncthreads();
        #pragma unroll
        for (int i = 0; i < 2; ++i) {
            const int row = (wave * 2 + i) * 16 + srow;
            if constexpr (HEADOUT) {
                const float* xp = (const float*)Asrc +
                                  (size_t)(bm + row) * 512 + k0 + scol;
                const float4 v0 = *(const float4*)(xp);
                const float4 v1 = *(const float4*)(xp + 4);
                union { unsigned int u[4]; short8 s; } pk;
                pk.u[0] = pk2bf(v0.x, v0.y);
                pk.u[1] = pk2bf(v0.z, v0.w);
                pk.u[2] = pk2bf(v1.x, v1.y);
                pk.u[3] = pk2bf(v1.z, v1.w);
                *(short8*)(&As[row * 32 + scol]) = pk.s;
            } else {
                const short8 v = *(const short8*)((const unsigned short*)Asrc +
                                  (size_t)(bm + row) * 512 + k0 + scol);
                *(short8*)(&As[row * 32 + scol]) = v;
            }
        }
        {
            const int row = wave * 16 + srow;
            const short8 v = *(const short8*)(Wp + (size_t)(bn + row) * 512 + k0 + scol);
            *(short8*)(&Bs[row * 32 + scol]) = v;
        }
        __syncthreads();

        short8 a[4], bfr[2];
        #pragma unroll
        for (int mi = 0; mi < 4; ++mi)
            a[mi] = *(const short8*)(&As[(wr * 64 + mi * 16 + c) * 32 + g * 8]);
        #pragma unroll
        for (int ni = 0; ni < 2; ++ni)
            bfr[ni] = *(const short8*)(&Bs[(wc * 32 + ni * 16 + c) * 32 + g * 8]);
        #pragma unroll
        for (int mi = 0; mi < 4; ++mi)
            #pragma unroll
            for (int ni = 0; ni < 2; ++ni)
                acc[mi][ni] = MFMA16(a[mi], bfr[ni], acc[mi][ni], 0, 0, 0);
    }

    #pragma unroll
    for (int mi = 0; mi < 4; ++mi) {
        #pragma unroll
        for (int ni = 0; ni < 2; ++ni) {
            const int n = bn + wc * 32 + ni * 16 + c;
            const float bias = bp[n];
            float v[4];
            #pragma unroll
            for (int r = 0; r < 4; ++r) {
                v[r] = fmaxf(acc[mi][ni][r] + bias, 0.0f);
                if (HEADOUT && z == 0) v[r] *= SC2;   // pre-scale Q
            }
            const int mbase = bm + wr * 64 + mi * 16 + 4 * g;
            if constexpr (HEADOUT) {
                const int bb = mbase >> 11, ss = mbase & 2047;
                const int hh = n >> 6, hd = n & 63;
                if (z == 2) {
                    union { ushort4 u; unsigned short s[4]; } pk;
                    #pragma unroll
                    for (int r = 0; r < 4; ++r) pk.s[r] = f32_to_bf16_bits(v[r]);
                    *reinterpret_cast<ushort4*>(
                        Hout + (size_t)2 * HEADMAT +
                        (size_t)(bb * Hc + hh) * Sc * HDc +
                        (size_t)(ss >> 5) * (HDc * 32) + hd * 32 + (ss & 31)) = pk.u;
                } else {
                    #pragma unroll
                    for (int r = 0; r < 4; ++r)
                        Hout[(size_t)z * HEADMAT +
                             (((size_t)(bb * Hc + hh) * Sc + ss + r) * HDc + hd)] =
                            f32_to_bf16_bits(v[r]);
                }
            } else {
                #pragma unroll
                for (int r = 0; r < 4; ++r)
                    Yf[(size_t)(mbase + r) * 512 + n] = v[r];
            }
        }
    }
}

// ---------------------------------------------------------------------------
// Split-K flash attention, v16 = R18/R20 body + K software pipelining +
// isolated defer-rescale (T13, THR=8 in log2 domain).
// R21 ablation: phases stack ADDITIVELY on the wave's serial chain (skeleton
// 15-29us, +softmax/pack/PV to 57.5). Exposed link #1: K loads consumed
// immediately by QK MFMA (~200cy L2 latency paid per iter). Fix: prefetch
// next iteration's K fragments right after this iteration's QK -- the wait
// then sits behind a full iteration of independent work. Exposed link #2:
// 32-mul rescale most iters -> THR=8 skips it (p <= 2^8, f32/bf16-safe).
// ---------------------------------------------------------------------------
__global__ __launch_bounds__(256)
void attn_mfma(const short* __restrict__ Qh, const short* __restrict__ Kh,
               const short* __restrict__ Vb, const int* __restrict__ mask,
               unsigned short* __restrict__ Ob)
{
    // per-wave overlay: Lacc[64][33] f32 (8448B); Lml 256B/wave
    __shared__ __align__(16) char smem[4 * 8448 + 4 * 256];

    const int lane = threadIdx.x & 63;
    const int wave = threadIdx.x >> 6;
    const int bid  = blockIdx.x;                    // 1024 blocks
    const int swz  = (bid & 7) * 128 + (bid >> 3);  // XCD-chunked, bijective
    const int t    = 63 - (swz & 63);               // LPT: big tiles first
    const int h    = (swz >> 6) & 7;
    const int b    = swz >> 9;
    const int q0   = t * 32;
    const int r32  = lane & 31;
    const int hi   = lane >> 5;

    char*  wreg = smem + wave * 8448;
    float* Lml  = (float*)(smem + 4 * 8448 + wave * 256);

    const size_t headoff = (size_t)(b * Hc + h) * Sc * HDc;
    const short* Qp = Qh + headoff;
    const short* Kp = Kh + headoff;
    const short* Vp = Vb + headoff;                 // blocked [S/32][64][32]
    const int* mb = mask + b * Sc;

    // first unmasked key (block-uniform)
    int fb = Sc;
    for (int base = 0; base < Sc; base += 64) {
        unsigned long long bal = __ballot(mb[base + lane] != 0);
        if (bal) { fb = base + (__ffsll(bal) - 1); break; }
    }
    const int kmax = (fb <= q0) ? (q0 + 32) : Sc;
    const int kend = (kmax + 31) & ~31;
    const int nT   = kend >> 5;
    const int tpw  = (nT + 3) >> 2;
    const int kbeg = wave * tpw * 32;
    const int kfin = min(kend, kbeg + tpw * 32);

    // Q fragments (B-operand): Q[q=r32][d = 16j + 8hi + e]  (pre-scaled)
    short8 qf[4];
    #pragma unroll
    for (int j = 0; j < 4; ++j)
        qf[j] = *(const short8*)(Qp + (size_t)(q0 + r32) * HDc + j * 16 + hi * 8);

    f32x16 acc0 = {0,0,0,0,0,0,0,0,0,0,0,0,0,0,0,0};
    f32x16 acc1 = {0,0,0,0,0,0,0,0,0,0,0,0,0,0,0,0};
    float m = -1e30f, l = 0.0f;

    // per-lane V offsets within a panel (elements)
    const int vo0 = r32 * 32 + 8 * hi;
    const int vo1 = (32 + r32) * 32 + 8 * hi;

    // --- K pipeline prologue: fragments for the first iteration
    const size_t krow = (size_t)r32 * HDc + hi * 8;
    short8 kf[4];
    #pragma unroll
    for (int j = 0; j < 4; ++j)
        kf[j] = *(const short8*)(Kp + (size_t)kbeg * HDc + krow + j * 16);

    for (int k0 = kbeg; k0 < kfin; k0 += 32) {
        // --- V fragments: blocked-panel loads (used at bottom; latency hides)
        const short* vpan = Vp + (size_t)k0 * 64;
        const short8 va0 = *(const short8*)(vpan + vo0);
        const short8 va1 = *(const short8*)(vpan + vo0 + 16);
        const short8 vb0 = *(const short8*)(vpan + vo1);
        const short8 vb1 = *(const short8*)(vpan + vo1 + 16);

        // --- QK^T with pipelined K fragments
        f32x16 s = {0,0,0,0,0,0,0,0,0,0,0,0,0,0,0,0};
        #pragma unroll
        for (int j = 0; j < 4; ++j)
            s = MFMA32(kf[j], qf[j], s, 0, 0, 0);

        // --- prefetch NEXT iteration's K fragments (clamped, branchless);
        //     their vmcnt wait lands after softmax/pack/PV of this iteration
        const int kn = (k0 + 32 < kfin) ? (k0 + 32) : kbeg;
        #pragma unroll
        for (int j = 0; j < 4; ++j)
            kf[j] = *(const short8*)(Kp + (size_t)kn * HDc + krow + j * 16);

        // --- padding-mask bits (ballot -> wave-uniform word)
        const unsigned long long bal = __ballot(mb[k0 + r32] != 0);
        const unsigned int mloc = ((unsigned int)bal) >> (4 * hi);

        float e[16];
        float tmax = -1e30f;
        if (k0 + 31 > q0) {   // diagonal tile: causal compares needed
            #pragma unroll
            for (int r = 0; r < 16; ++r) {
                const int cr0 = (r & 3) + 8 * (r >> 2);
                float ev = s[r];
                if (!((mloc >> cr0) & 1))            ev -= NEG2;
                if (k0 + cr0 + 4 * hi > q0 + r32)    ev -= NEG2;
                e[r] = ev;
                tmax = fmaxf(tmax, ev);
            }
        } else {
            #pragma unroll
            for (int r = 0; r < 16; ++r) {
                const int cr0 = (r & 3) + 8 * (r >> 2);
                float ev = s[r];
                if (!((mloc >> cr0) & 1))            ev -= NEG2;
                e[r] = ev;
                tmax = fmaxf(tmax, ev);
            }
        }
        tmax = fmaxf(tmax, __shfl_xor(tmax, 32));   // full-row max

        // --- defer-rescale (T13, THR=8): p bounded by 2^8, skip most rescales
        if (__any(tmax > m + 8.0f)) {
            const float mn   = fmaxf(m, tmax);
            const float corr = __builtin_exp2f(m - mn);
            m = mn; l *= corr;
            acc0 *= corr;
            acc1 *= corr;
        }

        float ps = 0.f;
        #pragma unroll
        for (int r = 0; r < 16; ++r) {
            e[r] = __builtin_exp2f(e[r] - m);   // e[] now holds p
            ps += e[r];
        }
        l += ps;

        // --- pack P pairs (HW cvt_pk) and exchange across lane-halves
        const unsigned int A0 = pk2bf(e[0],  e[1]),  B0 = pk2bf(e[2],  e[3]);
        const unsigned int C0 = pk2bf(e[4],  e[5]),  D0 = pk2bf(e[6],  e[7]);
        const unsigned int A1 = pk2bf(e[8],  e[9]),  B1 = pk2bf(e[10], e[11]);
        const unsigned int C1 = pk2bf(e[12], e[13]), D1 = pk2bf(e[14], e[15]);
        const unsigned int A0s = (unsigned int)__shfl_xor((int)A0, 32);
        const unsigned int B0s = (unsigned int)__shfl_xor((int)B0, 32);
        const unsigned int C0s = (unsigned int)__shfl_xor((int)C0, 32);
        const unsigned int D0s = (unsigned int)__shfl_xor((int)D0, 32);
        const unsigned int A1s = (unsigned int)__shfl_xor((int)A1, 32);
        const unsigned int B1s = (unsigned int)__shfl_xor((int)B1, 32);
        const unsigned int C1s = (unsigned int)__shfl_xor((int)C1, 32);
        const unsigned int D1s = (unsigned int)__shfl_xor((int)D1, 32);

        union { unsigned int u[4]; short8 s8; } P0, P1;
        P0.u[0] = hi ? C0s : A0;  P0.u[1] = hi ? D0s : B0;
        P0.u[2] = hi ? C0  : A0s; P0.u[3] = hi ? D0  : B0s;
        P1.u[0] = hi ? C1s : A1;  P1.u[1] = hi ? D1s : B1;
        P1.u[2] = hi ? C1  : A1s; P1.u[3] = hi ? D1  : B1s;

        // --- PV: O^T += V^T_frag x P_frag
        acc0 = MFMA32(va0, P0.s8, acc0, 0, 0, 0);
        acc0 = MFMA32(va1, P1.s8, acc0, 0, 0, 0);
        acc1 = MFMA32(vb0, P0.s8, acc1, 0, 0, 0);
        acc1 = MFMA32(vb1, P1.s8, acc1, 0, 0, 0);
    }

    l += __shfl_xor(l, 32);   // full-row denominator for this wave

    // dump partials into OWN overlay region
    {
        float* Lacc = (float*)wreg;   // [64][33]
        #pragma unroll
        for (int r = 0; r < 16; ++r) {
            Lacc[lane * 33 + r]      = acc0[r];
            Lacc[lane * 33 + 16 + r] = acc1[r];
        }
        if (lane < 32) { Lml[lane] = m; Lml[32 + lane] = l; }
    }
    __syncthreads();

    // combine: per-lane weights (q = r32); wave w handles regs [8w, 8w+8)
    float mu[4], lu[4], M = -1e30f;
    #pragma unroll
    for (int u = 0; u < 4; ++u) {
        const float* LmlU = (const float*)(smem + 4 * 8448 + u * 256);
        mu[u] = LmlU[r32];
        lu[u] = LmlU[32 + r32];
        M = fmaxf(M, mu[u]);
    }
    float wgt[4], L = 0.f;
    #pragma unroll
    for (int u = 0; u < 4; ++u) {
        wgt[u] = __builtin_exp2f(mu[u] - M);
        L += wgt[u] * lu[u];
    }
    const float invL = 1.0f / L;

    #pragma unroll
    for (int jj = 0; jj < 8; ++jj) {
        const int j = wave * 8 + jj;
        float o = 0.f;
        #pragma unroll
        for (int u = 0; u < 4; ++u)
            o += wgt[u] * ((const float*)(smem + u * 8448))[lane * 33 + j];
        const int j16 = j & 15;
        const int d = (j16 & 3) + 8 * (j16 >> 2) + 4 * hi + 32 * (j >> 4);
        Ob[(size_t)(b * Sc + q0 + r32) * Dc + h * HDc + d] =
            f32_to_bf16_bits(o * invL);
    }
}

// ---------------------------------------------------------------------------
extern "C" void kernel_launch(void* const* d_in, const int* in_sizes, int n_in,
                              void* d_out, int out_size, void* d_ws, size_t ws_size,
                              hipStream_t stream) {
    const float* x  = (const float*)d_in[0];
    const int* mask = (const int*)d_in[1];
    const float* Wq = (const float*)d_in[2];
    const float* bq = (const float*)d_in[3];
    const float* Wk = (const float*)d_in[4];
    const float* bk = (const float*)d_in[5];
    const float* Wv = (const float*)d_in[6];
    const float* bv = (const float*)d_in[7];
    const float* Wo = (const float*)d_in[8];
    const float* bo = (const float*)d_in[9];
    float* out = (float*)d_out;   // reference output dtype is float32

    unsigned short* Wt = (unsigned short*)d_ws;          // 2 MB
    unsigned short* Qh = Wt + (size_t)4 * 512 * 512;     // head-major (xSC2)
    unsigned short* Kh = Qh + HEADMAT;                   // head-major
    unsigned short* Vb = Kh + HEADMAT;                   // BLOCKED panels
    unsigned short* Ob = Vb + HEADMAT;

    transpose_w<<<dim3(8, 8, 4), dim3(256), 0, stream>>>(Wq, Wk, Wv, Wo, Wt);
    gemm_tile<true><<<dim3(8, Mtot / 128, 3), dim3(256), 0, stream>>>(
        x, Wt, bq, bk, bv, Qh, nullptr);
    attn_mfma<<<dim3(1024), dim3(256), 0, stream>>>(
        (const short*)Qh, (const short*)Kh, (const short*)Vb, mask, Ob);
    gemm_tile<false><<<dim3(8, Mtot / 128, 1), dim3(256), 0, stream>>>(
        Ob, Wt + (size_t)3 * 512 * 512, bo, bo, bo, nullptr, out);
}